// Round 16
// baseline (473.377 us; speedup 1.0000x reference)
//
#include <hip/hip_runtime.h>
#include <math.h>

#define NNODES 100000
#define NEDGES 3200000
#define ETOT   (NEDGES + NNODES)
#define IN_DIM 128
#define NH1    8
#define NC1    8
#define HC     64
#define OUTC   2
#define NEGSL  0.2f
#define L2E    1.44269504f

// counting-sort CSR build parameters
#define NBUCK 391                 // ceil(NNODES/256) coarse buckets (dst>>8)
#define EPB   4096                // edges per block in hist/scatter
#define NBLK  782                 // ceil(NEDGES/EPB)
#define TOTC  (NBUCK * NBLK)      // 305762 (bucket-major counts array)

// ---------------- CSR build (two-level LDS counting sort) ----------------

__global__ __launch_bounds__(256) void histA(const int* __restrict__ ei,
                                             int* __restrict__ carr) {
    __shared__ int lh[NBUCK];
    int tid = threadIdx.x;
    for (int i = tid; i < NBUCK; i += 256) lh[i] = 0;
    __syncthreads();
    const int* dptr = ei + NEDGES;
    int base = blockIdx.x * EPB;
#pragma unroll
    for (int i = 0; i < EPB / 1024; i++) {
        int idx = base + i * 1024 + tid * 4;
        if (idx < NEDGES) {
            int4 d4 = *(const int4*)&dptr[idx];
            atomicAdd(&lh[d4.x >> 8], 1);
            atomicAdd(&lh[d4.y >> 8], 1);
            atomicAdd(&lh[d4.z >> 8], 1);
            atomicAdd(&lh[d4.w >> 8], 1);
        }
    }
    __syncthreads();
    for (int i = tid; i < NBUCK; i += 256)
        carr[i * NBLK + blockIdx.x] = lh[i];
}

__global__ __launch_bounds__(256) void scanA(int* __restrict__ carr,
                                             int* __restrict__ bsums) {
    int gid = blockIdx.x * 256 + threadIdx.x;
    int v = (gid < TOTC) ? carr[gid] : 0;
    int lane = threadIdx.x & 63, w = threadIdx.x >> 6;
    int x = v;
    for (int off = 1; off < 64; off <<= 1) {
        int y = __shfl_up(x, off, 64);
        if (lane >= off) x += y;
    }
    __shared__ int wt[4];
    if (lane == 63) wt[w] = x;
    __syncthreads();
    int add = 0;
    for (int i = 0; i < w; i++) add += wt[i];
    int incl = x + add;
    if (gid < TOTC) carr[gid] = incl - v;
    if (threadIdx.x == 255) bsums[blockIdx.x] = incl;
}

__global__ __launch_bounds__(1024) void scanB(int* __restrict__ bsums, int nb) {
    int tid = threadIdx.x;
    int base = tid * 4;
    int v[4]; int tot = 0;
#pragma unroll
    for (int j = 0; j < 4; j++) {
        v[j] = (base + j < nb) ? bsums[base + j] : 0;
        tot += v[j];
    }
    int lane = tid & 63, w = tid >> 6;
    int x = tot;
    for (int off = 1; off < 64; off <<= 1) {
        int y = __shfl_up(x, off, 64);
        if (lane >= off) x += y;
    }
    __shared__ int wt[16];
    if (lane == 63) wt[w] = x;
    __syncthreads();
    int add = 0;
    for (int i = 0; i < w; i++) add += wt[i];
    int pre = x + add - tot;
#pragma unroll
    for (int j = 0; j < 4; j++) {
        if (base + j < nb) bsums[base + j] = pre;
        pre += v[j];
    }
}

__global__ __launch_bounds__(256) void scanC(int* __restrict__ carr,
                                             const int* __restrict__ bsums) {
    int gid = blockIdx.x * 256 + threadIdx.x;
    if (gid < TOTC) carr[gid] += bsums[gid >> 8];
}

__global__ __launch_bounds__(256) void scatC(const int* __restrict__ ei,
                                             const int* __restrict__ soff,
                                             int* __restrict__ ebuf) {
    __shared__ int soffL[NBUCK];
    __shared__ int lh[NBUCK];
    int tid = threadIdx.x;
    for (int i = tid; i < NBUCK; i += 256) {
        soffL[i] = soff[i * NBLK + blockIdx.x];
        lh[i] = 0;
    }
    __syncthreads();
    int base = blockIdx.x * EPB;
#pragma unroll
    for (int i = 0; i < EPB / 1024; i++) {
        int idx = base + i * 1024 + tid * 4;
        if (idx < NEDGES) {
            int4 s4 = *(const int4*)&ei[idx];
            int4 d4 = *(const int4*)&ei[NEDGES + idx];
            int b0 = d4.x >> 8, b1 = d4.y >> 8, b2 = d4.z >> 8, b3 = d4.w >> 8;
            int r0 = atomicAdd(&lh[b0], 1);
            int r1 = atomicAdd(&lh[b1], 1);
            int r2 = atomicAdd(&lh[b2], 1);
            int r3 = atomicAdd(&lh[b3], 1);
            ebuf[soffL[b0] + r0] = s4.x | ((d4.x & 255) << 17);
            ebuf[soffL[b1] + r1] = s4.y | ((d4.y & 255) << 17);
            ebuf[soffL[b2] + r2] = s4.z | ((d4.z & 255) << 17);
            ebuf[soffL[b3] + r3] = s4.w | ((d4.w & 255) << 17);
        }
    }
}

__global__ __launch_bounds__(256) void buildD(const int* __restrict__ soff,
                                              const int* __restrict__ ebuf,
                                              int* __restrict__ rowoff,
                                              int* __restrict__ srcs) {
    int b = blockIdx.x, tid = threadIdx.x;
    int nb = min(256, NNODES - b * 256);
    int ebeg = soff[b * NBLK];
    int eend = (b == NBUCK - 1) ? NEDGES : soff[(b + 1) * NBLK];
    __shared__ int cnt2[256];
    __shared__ int rowL[256];
    __shared__ int wsum[4];
    cnt2[tid] = 0;
    __syncthreads();
    for (int e = ebeg + tid; e < eend; e += 256)
        atomicAdd(&cnt2[(ebuf[e] >> 17) & 255], 1);
    __syncthreads();
    int v = (tid < nb) ? cnt2[tid] + 1 : 0;
    int lane = tid & 63, w = tid >> 6;
    int x = v;
    for (int off = 1; off < 64; off <<= 1) {
        int y = __shfl_up(x, off, 64);
        if (lane >= off) x += y;
    }
    if (lane == 63) wsum[w] = x;
    __syncthreads();
    int add = 0;
    for (int i = 0; i < w; i++) add += wsum[i];
    int fbase = ebeg + b * 256;
    int row = fbase + x + add - v;
    if (tid < nb) {
        rowL[tid] = row;
        int gnode = b * 256 + tid;
        rowoff[gnode] = row;
        srcs[row + cnt2[tid]] = gnode;
        if (gnode == NNODES - 1) rowoff[NNODES] = ETOT;
    }
    __syncthreads();
    cnt2[tid] = 0;
    __syncthreads();
    for (int e = ebeg + tid; e < eend; e += 256) {
        int wv = ebuf[e];
        int dl = (wv >> 17) & 255;
        int r = atomicAdd(&cnt2[dl], 1);
        srcs[rowL[dl] + r] = wv & 0x1FFFF;
    }
}

// ---------------- layer 1 linear + attention logit exponentials ----------------
// SHARD-MAJOR outputs: h1e[q][node][8] bf16 (1.6MB/shard), alEq[q][node]
// float2 (0.8MB/shard) — each shard fits a 4MB per-XCD L2 for agg1e.

__global__ __launch_bounds__(256) void gemm1(const float* __restrict__ x,
                                             const float* __restrict__ W1,
                                             const float* __restrict__ a1s,
                                             const float* __restrict__ a1d,
                                             unsigned short* __restrict__ h1e,
                                             float2* __restrict__ alEq,
                                             float* __restrict__ al1d) {
    __shared__ float sW[IN_DIM * HC];   // 32 KB
    int tid = threadIdx.x;
    const float4* W4 = (const float4*)W1;
    float4* sW4 = (float4*)sW;
#pragma unroll
    for (int i = 0; i < 8; i++)
        sW4[tid + i * 256] = W4[tid + i * 256];
    __syncthreads();

    int w = __builtin_amdgcn_readfirstlane(tid >> 6);
    int lane = tid & 63;
    int node0 = blockIdx.x * 16 + w * 4;       // 6250 blocks * 16 = 100000 exact
    const float* xr = x + (size_t)node0 * IN_DIM;

    float acc0 = 0.f, acc1 = 0.f, acc2 = 0.f, acc3 = 0.f;
#pragma unroll 8
    for (int k = 0; k < IN_DIM; k++) {
        float wv = sW[k * HC + lane];
        acc0 = fmaf(xr[k], wv, acc0);
        acc1 = fmaf(xr[IN_DIM + k], wv, acc1);
        acc2 = fmaf(xr[2 * IN_DIM + k], wv, acc2);
        acc3 = fmaf(xr[3 * IN_DIM + k], wv, acc3);
    }

    float accs[4] = {acc0, acc1, acc2, acc3};
    int head = lane >> 3, c = lane & 7;
    float as = a1s[head * NC1 + c], adv = a1d[head * NC1 + c];
#pragma unroll
    for (int n = 0; n < 4; n++) {
        int node = node0 + n;
        unsigned int u = __float_as_uint(accs[n]);
        // shard-major: shard (lane>>3) holds channels (lane>>3)*8..+7
        h1e[((size_t)head * NNODES + node) * 8 + c] =
            (unsigned short)((u + 0x7FFF + ((u >> 16) & 1)) >> 16);  // RNE bf16
        float ps = accs[n] * as;
        float pd = accs[n] * adv;
        for (int off = 1; off < 8; off <<= 1) {
            ps += __shfl_xor(ps, off, 64);
            pd += __shfl_xor(pd, off, 64);
        }
        if (c == 0) {
            alEq[(size_t)head * NNODES + node] =
                make_float2(exp2f(ps * L2E), exp2f(ps * (NEGSL * L2E)));
            al1d[node * NH1 + head] = pd;
        }
    }
}

// ---------------- layer 1 aggregation, channel-sharded with XCD affinity ----
// shard q = blockIdx.x & 7 (empirical bid->XCD round-robin): each XCD's L2
// holds only ITS shard's h1e plane (1.6MB) + alEq plane (0.8MB) -> random
// gathers become L2 hits instead of the ~2.5TB/s random-line L3 path.
// Wave = one node; lane = e*4 + c: e = edge slot (0..15), c = channel pair
// (channels 2c,2c+1 of the shard; the shard IS one head -> ald uniform).
// Epilogue: o=acc/den+b1, ELU, partial W2 dot -> part[q][node].

__global__ __launch_bounds__(256) void agg1e(const unsigned short* __restrict__ h1e,
                                             const float2* __restrict__ alEq,
                                             const float* __restrict__ al1d,
                                             const float* __restrict__ b1,
                                             const float* __restrict__ W2,
                                             const int* __restrict__ rowoff,
                                             const int* __restrict__ srcs,
                                             float2* __restrict__ part) {
    int q = blockIdx.x & 7;
    int w = threadIdx.x >> 6, lane = threadIdx.x & 63;
    int node = (blockIdx.x >> 3) * 4 + w;     // 8*25000 blocks, exact cover
    int e = lane >> 2, c = lane & 3;
    const unsigned short* hrow = h1e + (size_t)q * NNODES * 8;
    const float2* alp = alEq + (size_t)q * NNODES;
    float ald = al1d[node * NH1 + q];
    float E1d = exp2f(ald * L2E);
    float E2d = exp2f(ald * (NEGSL * L2E));
    int beg = __builtin_amdgcn_readfirstlane(rowoff[node]);
    int end = __builtin_amdgcn_readfirstlane(rowoff[node + 1]);

    float den = 0.f, acc0 = 0.f, acc1 = 0.f;
    for (int i = beg; i < end; i += 16) {
        int idx = i + e;
        bool valid = idx < end;
        int s = srcs[valid ? idx : end - 1];
        float2 ea = alp[s];                                   // 8B, L2-resident
        unsigned int hv = *(const unsigned int*)&hrow[s * 8 + 2 * c]; // 2 bf16
        float p = fmaxf(ea.x * E1d, ea.y * E2d);
        p = valid ? p : 0.f;
        den += p;
        acc0 = fmaf(p, __uint_as_float(hv << 16), acc0);
        acc1 = fmaf(p, __uint_as_float(hv & 0xFFFF0000u), acc1);
    }
    // reduce over the 16 edge slots (lane bits 2..5)
    den  += __shfl_xor(den, 4, 64);   den  += __shfl_xor(den, 8, 64);
    den  += __shfl_xor(den, 16, 64);  den  += __shfl_xor(den, 32, 64);
    acc0 += __shfl_xor(acc0, 4, 64);  acc0 += __shfl_xor(acc0, 8, 64);
    acc0 += __shfl_xor(acc0, 16, 64); acc0 += __shfl_xor(acc0, 32, 64);
    acc1 += __shfl_xor(acc1, 4, 64);  acc1 += __shfl_xor(acc1, 8, 64);
    acc1 += __shfl_xor(acc1, 16, 64); acc1 += __shfl_xor(acc1, 32, 64);

    float rd = 1.f / den;
    int ch = 8 * q + 2 * c;                    // global channel of this pair
    float2 b1v = *(const float2*)&b1[ch];
    float o0 = fmaf(acc0, rd, b1v.x);
    float o1 = fmaf(acc1, rd, b1v.y);
    o0 = (o0 > 0.f) ? o0 : expm1f(o0);         // ELU
    o1 = (o1 > 0.f) ? o1 : expm1f(o1);
    float4 w2v = *(const float4*)&W2[2 * ch];  // rows ch, ch+1
    float p0 = o0 * w2v.x + o1 * w2v.z;
    float p1 = o0 * w2v.y + o1 * w2v.w;
    p0 += __shfl_xor(p0, 1, 64);  p0 += __shfl_xor(p0, 2, 64);
    p1 += __shfl_xor(p1, 1, 64);  p1 += __shfl_xor(p1, 2, 64);
    if (lane == 0) part[(size_t)q * NNODES + node] = make_float2(p0, p1);
}

// combine the 8 shard partials -> layer-2 node data
__global__ __launch_bounds__(256) void fin1(const float2* __restrict__ part,
                                            const float* __restrict__ a2s,
                                            const float* __restrict__ a2d,
                                            float4* __restrict__ nd2,
                                            float* __restrict__ al2d) {
    int n = blockIdx.x * 256 + threadIdx.x;
    if (n >= NNODES) return;
    float s0 = 0.f, s1 = 0.f;
#pragma unroll
    for (int q = 0; q < 8; q++) {
        float2 pp = part[(size_t)q * NNODES + n];
        s0 += pp.x; s1 += pp.y;
    }
    float l2s = s0 * a2s[0] + s1 * a2s[1];
    float l2d = s0 * a2d[0] + s1 * a2d[1];
    nd2[n] = make_float4(exp2f(l2s * L2E), exp2f(l2s * (NEGSL * L2E)), s0, s1);
    al2d[n] = l2d;
}

// ---------------- layer 2 aggregation (wave per node, lane per edge) ----------------

__global__ __launch_bounds__(256) void agg2(const float4* __restrict__ nd2,
                                            const float* __restrict__ al2d,
                                            const float* __restrict__ b2,
                                            const int* __restrict__ rowoff,
                                            const int* __restrict__ srcs,
                                            float* __restrict__ out) {
    int w = threadIdx.x >> 6, lane = threadIdx.x & 63;
    int n = blockIdx.x * 4 + w;
    if (n >= NNODES) return;
    float ald = al2d[n];
    float E1d = exp2f(ald * L2E);
    float E2d = exp2f(ald * (NEGSL * L2E));
    int beg = rowoff[n], end = rowoff[n + 1];
    float den = 0.f, a0 = 0.f, a1 = 0.f;
    for (int idx = beg + lane; idx < end; idx += 64) {
        int s = srcs[idx];
        float4 nd = nd2[s];
        float p = fmaxf(nd.x * E1d, nd.y * E2d);
        den += p;
        a0 = fmaf(p, nd.z, a0);
        a1 = fmaf(p, nd.w, a1);
    }
    for (int off = 1; off < 64; off <<= 1) {
        den += __shfl_xor(den, off, 64);
        a0  += __shfl_xor(a0, off, 64);
        a1  += __shfl_xor(a1, off, 64);
    }
    if (lane == 0) {
        out[n * 2 + 0] = a0 / den + b2[0];
        out[n * 2 + 1] = a1 / den + b2[1];
    }
}

// ---------------- launch ----------------

extern "C" void kernel_launch(void* const* d_in, const int* in_sizes, int n_in,
                              void* d_out, int out_size, void* d_ws, size_t ws_size,
                              hipStream_t stream) {
    const float* x   = (const float*)d_in[0];
    const int*   ei  = (const int*)  d_in[1];
    // d_in[2] = edge_attr (unused by reference)
    const float* W1  = (const float*)d_in[3];
    const float* a1s = (const float*)d_in[4];
    const float* a1d = (const float*)d_in[5];
    const float* b1  = (const float*)d_in[6];
    const float* W2  = (const float*)d_in[7];
    const float* a2s = (const float*)d_in[8];
    const float* a2d = (const float*)d_in[9];
    const float* b2  = (const float*)d_in[10];
    float* out = (float*)d_out;

    // workspace layout. CSR scratch (ebuf/carr/bsums) aliases the h1e+alEq
    // region — both dead until gemm1, which runs after buildD.
    char* ws = (char*)d_ws;
    unsigned short* h1e = (unsigned short*)ws;               // 8 planes * N*8 bf16 (12.8MB)
    float2* alEq  = (float2*)(ws + (size_t)NNODES * HC * 2); // 8 planes * N float2 (6.4MB)
    float* al1d_  = (float*)(alEq + (size_t)NNODES * NH1);   // N*8 (3.2MB)
    float4* nd2   = (float4*)(al1d_ + (size_t)NNODES * NH1); // N float4 (1.6MB)
    float* al2d_  = (float*)(nd2 + NNODES);                  // N
    int* rowoff   = (int*)(al2d_ + NNODES);                  // N+1
    int* srcs     = rowoff + NNODES + 1;                     // E+N (13.2MB)
    float2* part  = (float2*)(srcs + ETOT);                  // 8*N float2 (6.4MB)
    // CSR scratch aliases h1e..alEq (19.2MB >= 14.1MB needed)
    int* ebuf     = (int*)ws;                                // NEDGES (12.8MB)
    int* carr     = ebuf + NEDGES;                           // TOTC (1.22MB)
    int* bsums    = carr + TOTC;                             // ~1195 ints

    const int NB_SC  = (TOTC + 255) / 256;            // 1195
    const int NB_N   = (NNODES + 255) / 256;          // 391
    const int NB_N4  = (NNODES + 3) / 4;              // 25000
    const int NB_G   = NNODES / 16;                   // 6250 (exact)

    // CSR build (LDS counting sort; no global atomics)
    histA<<<NBLK, 256, 0, stream>>>(ei, carr);
    scanA<<<NB_SC, 256, 0, stream>>>(carr, bsums);
    scanB<<<1, 1024, 0, stream>>>(bsums, NB_SC);
    scanC<<<NB_SC, 256, 0, stream>>>(carr, bsums);
    scatC<<<NBLK, 256, 0, stream>>>(ei, carr, ebuf);
    buildD<<<NBUCK, 256, 0, stream>>>(carr, ebuf, rowoff, srcs);

    // layer 1 linear + logit exponentials (shard-major layout)
    gemm1<<<NB_G, 256, 0, stream>>>(x, W1, a1s, a1d, h1e, alEq, al1d_);

    // layer 1 aggregation, 8 channel shards with XCD affinity
    agg1e<<<8 * NB_N4, 256, 0, stream>>>(h1e, alEq, al1d_, b1, W2,
                                         rowoff, srcs, part);
    fin1<<<NB_N, 256, 0, stream>>>(part, a2s, a2d, nd2, al2d_);

    // layer 2 aggregation -> output
    agg2<<<NB_N4, 256, 0, stream>>>(nd2, al2d_, b2, rowoff, srcs, out);
}

// Round 17
// 276.058 us; speedup vs baseline: 1.7148x; 1.7148x over previous
//
#include <hip/hip_runtime.h>
#include <math.h>

#define NNODES 100000
#define NEDGES 3200000
#define ETOT   (NEDGES + NNODES)
#define IN_DIM 128
#define NH1    8
#define NC1    8
#define HC     64
#define OUTC   2
#define NEGSL  0.2f
#define L2E    1.44269504f

// counting-sort CSR build parameters
#define NBUCK 391                 // ceil(NNODES/256) coarse buckets (dst>>8)
#define EPB   4096                // edges per block in hist/scatter
#define NBLK  782                 // ceil(NEDGES/EPB)
#define TOTC  (NBUCK * NBLK)      // 305762 (bucket-major counts array)

// ---------------- CSR build (two-level LDS counting sort) ----------------

__global__ __launch_bounds__(256) void histA(const int* __restrict__ ei,
                                             int* __restrict__ carr) {
    __shared__ int lh[NBUCK];
    int tid = threadIdx.x;
    for (int i = tid; i < NBUCK; i += 256) lh[i] = 0;
    __syncthreads();
    const int* dptr = ei + NEDGES;
    int base = blockIdx.x * EPB;
#pragma unroll
    for (int i = 0; i < EPB / 1024; i++) {
        int idx = base + i * 1024 + tid * 4;
        if (idx < NEDGES) {
            int4 d4 = *(const int4*)&dptr[idx];
            atomicAdd(&lh[d4.x >> 8], 1);
            atomicAdd(&lh[d4.y >> 8], 1);
            atomicAdd(&lh[d4.z >> 8], 1);
            atomicAdd(&lh[d4.w >> 8], 1);
        }
    }
    __syncthreads();
    for (int i = tid; i < NBUCK; i += 256)
        carr[i * NBLK + blockIdx.x] = lh[i];
}

__global__ __launch_bounds__(256) void scanA(int* __restrict__ carr,
                                             int* __restrict__ bsums) {
    int gid = blockIdx.x * 256 + threadIdx.x;
    int v = (gid < TOTC) ? carr[gid] : 0;
    int lane = threadIdx.x & 63, w = threadIdx.x >> 6;
    int x = v;
    for (int off = 1; off < 64; off <<= 1) {
        int y = __shfl_up(x, off, 64);
        if (lane >= off) x += y;
    }
    __shared__ int wt[4];
    if (lane == 63) wt[w] = x;
    __syncthreads();
    int add = 0;
    for (int i = 0; i < w; i++) add += wt[i];
    int incl = x + add;
    if (gid < TOTC) carr[gid] = incl - v;
    if (threadIdx.x == 255) bsums[blockIdx.x] = incl;
}

__global__ __launch_bounds__(1024) void scanB(int* __restrict__ bsums, int nb) {
    int tid = threadIdx.x;
    int base = tid * 4;
    int v[4]; int tot = 0;
#pragma unroll
    for (int j = 0; j < 4; j++) {
        v[j] = (base + j < nb) ? bsums[base + j] : 0;
        tot += v[j];
    }
    int lane = tid & 63, w = tid >> 6;
    int x = tot;
    for (int off = 1; off < 64; off <<= 1) {
        int y = __shfl_up(x, off, 64);
        if (lane >= off) x += y;
    }
    __shared__ int wt[16];
    if (lane == 63) wt[w] = x;
    __syncthreads();
    int add = 0;
    for (int i = 0; i < w; i++) add += wt[i];
    int pre = x + add - tot;
#pragma unroll
    for (int j = 0; j < 4; j++) {
        if (base + j < nb) bsums[base + j] = pre;
        pre += v[j];
    }
}

__global__ __launch_bounds__(256) void scanC(int* __restrict__ carr,
                                             const int* __restrict__ bsums) {
    int gid = blockIdx.x * 256 + threadIdx.x;
    if (gid < TOTC) carr[gid] += bsums[gid >> 8];
}

__global__ __launch_bounds__(256) void scatC(const int* __restrict__ ei,
                                             const int* __restrict__ soff,
                                             int* __restrict__ ebuf) {
    __shared__ int soffL[NBUCK];
    __shared__ int lh[NBUCK];
    int tid = threadIdx.x;
    for (int i = tid; i < NBUCK; i += 256) {
        soffL[i] = soff[i * NBLK + blockIdx.x];
        lh[i] = 0;
    }
    __syncthreads();
    int base = blockIdx.x * EPB;
#pragma unroll
    for (int i = 0; i < EPB / 1024; i++) {
        int idx = base + i * 1024 + tid * 4;
        if (idx < NEDGES) {
            int4 s4 = *(const int4*)&ei[idx];
            int4 d4 = *(const int4*)&ei[NEDGES + idx];
            int b0 = d4.x >> 8, b1 = d4.y >> 8, b2 = d4.z >> 8, b3 = d4.w >> 8;
            int r0 = atomicAdd(&lh[b0], 1);
            int r1 = atomicAdd(&lh[b1], 1);
            int r2 = atomicAdd(&lh[b2], 1);
            int r3 = atomicAdd(&lh[b3], 1);
            ebuf[soffL[b0] + r0] = s4.x | ((d4.x & 255) << 17);
            ebuf[soffL[b1] + r1] = s4.y | ((d4.y & 255) << 17);
            ebuf[soffL[b2] + r2] = s4.z | ((d4.z & 255) << 17);
            ebuf[soffL[b3] + r3] = s4.w | ((d4.w & 255) << 17);
        }
    }
}

__global__ __launch_bounds__(256) void buildD(const int* __restrict__ soff,
                                              const int* __restrict__ ebuf,
                                              int* __restrict__ rowoff,
                                              int* __restrict__ srcs) {
    int b = blockIdx.x, tid = threadIdx.x;
    int nb = min(256, NNODES - b * 256);
    int ebeg = soff[b * NBLK];
    int eend = (b == NBUCK - 1) ? NEDGES : soff[(b + 1) * NBLK];
    __shared__ int cnt2[256];
    __shared__ int rowL[256];
    __shared__ int wsum[4];
    cnt2[tid] = 0;
    __syncthreads();
    for (int e = ebeg + tid; e < eend; e += 256)
        atomicAdd(&cnt2[(ebuf[e] >> 17) & 255], 1);
    __syncthreads();
    int v = (tid < nb) ? cnt2[tid] + 1 : 0;
    int lane = tid & 63, w = tid >> 6;
    int x = v;
    for (int off = 1; off < 64; off <<= 1) {
        int y = __shfl_up(x, off, 64);
        if (lane >= off) x += y;
    }
    if (lane == 63) wsum[w] = x;
    __syncthreads();
    int add = 0;
    for (int i = 0; i < w; i++) add += wsum[i];
    int fbase = ebeg + b * 256;
    int row = fbase + x + add - v;
    if (tid < nb) {
        rowL[tid] = row;
        int gnode = b * 256 + tid;
        rowoff[gnode] = row;
        srcs[row + cnt2[tid]] = gnode;
        if (gnode == NNODES - 1) rowoff[NNODES] = ETOT;
    }
    __syncthreads();
    cnt2[tid] = 0;
    __syncthreads();
    for (int e = ebeg + tid; e < eend; e += 256) {
        int wv = ebuf[e];
        int dl = (wv >> 17) & 255;
        int r = atomicAdd(&cnt2[dl], 1);
        srcs[rowL[dl] + r] = wv & 0x1FFFF;
    }
}

// ---------------- layer 1 linear + attention logit exponentials ----------------

__global__ __launch_bounds__(256) void gemm1(const float* __restrict__ x,
                                             const float* __restrict__ W1,
                                             const float* __restrict__ a1s,
                                             const float* __restrict__ a1d,
                                             unsigned short* __restrict__ h1b,
                                             float2* __restrict__ alE,
                                             float* __restrict__ al1d) {
    __shared__ float sW[IN_DIM * HC];   // 32 KB
    int tid = threadIdx.x;
    const float4* W4 = (const float4*)W1;
    float4* sW4 = (float4*)sW;
#pragma unroll
    for (int i = 0; i < 8; i++)
        sW4[tid + i * 256] = W4[tid + i * 256];
    __syncthreads();

    int w = __builtin_amdgcn_readfirstlane(tid >> 6);
    int lane = tid & 63;
    int node0 = blockIdx.x * 16 + w * 4;       // 6250 blocks * 16 = 100000 exact
    const float* xr = x + (size_t)node0 * IN_DIM;

    float acc0 = 0.f, acc1 = 0.f, acc2 = 0.f, acc3 = 0.f;
#pragma unroll 8
    for (int k = 0; k < IN_DIM; k++) {
        float wv = sW[k * HC + lane];
        acc0 = fmaf(xr[k], wv, acc0);
        acc1 = fmaf(xr[IN_DIM + k], wv, acc1);
        acc2 = fmaf(xr[2 * IN_DIM + k], wv, acc2);
        acc3 = fmaf(xr[3 * IN_DIM + k], wv, acc3);
    }

    float accs[4] = {acc0, acc1, acc2, acc3};
    int head = lane >> 3, c = lane & 7;
    float as = a1s[head * NC1 + c], adv = a1d[head * NC1 + c];
#pragma unroll
    for (int n = 0; n < 4; n++) {
        int node = node0 + n;
        unsigned int u = __float_as_uint(accs[n]);
        h1b[node * HC + lane] =
            (unsigned short)((u + 0x7FFF + ((u >> 16) & 1)) >> 16);  // RNE bf16
        float ps = accs[n] * as;
        float pd = accs[n] * adv;
        for (int off = 1; off < 8; off <<= 1) {
            ps += __shfl_xor(ps, off, 64);
            pd += __shfl_xor(pd, off, 64);
        }
        if (c == 0) {
            alE[node * NH1 + head] = make_float2(exp2f(ps * L2E),
                                                 exp2f(ps * (NEGSL * L2E)));
            al1d[node * NH1 + head] = pd;
        }
    }
}

// ---------------- layer 1 aggregation (issue-minimized) ----------------
// wave per node; lane = channel (64). All addressing scalarized: srcs read
// as int4 (uniform addr) + readfirstlane; alE/h1b loads are SGPR-base +
// constant-voffset coalesced (alE: head*8 within a 64B row; h1b: lane*2
// within a 128B row). ~9 issue slots/edge vs R11's ~10+reductions; den is
// lane-local (no per-iteration cross-lane work). exp(LeakyReLU) == max of
// precomputed exponential products; softmax shift cancels in acc/den.

__global__ __launch_bounds__(256) void agg1(const unsigned short* __restrict__ h1b,
                                            const float2* __restrict__ alE,
                                            const float* __restrict__ al1d,
                                            const float* __restrict__ b1,
                                            const float* __restrict__ W2,
                                            const float* __restrict__ a2s,
                                            const float* __restrict__ a2d,
                                            const int* __restrict__ rowoff,
                                            const int* __restrict__ srcs,
                                            float4* __restrict__ nd2,
                                            float* __restrict__ al2d) {
    int w = threadIdx.x >> 6, lane = threadIdx.x & 63;
    int node = blockIdx.x * 4 + w;
    if (node >= NNODES) return;
    int head = lane >> 3;
    float ald = al1d[node * NH1 + head];
    float E1d = exp2f(ald * L2E);
    float E2d = exp2f(ald * (NEGSL * L2E));
    int beg = __builtin_amdgcn_readfirstlane(rowoff[node]);
    int end = __builtin_amdgcn_readfirstlane(rowoff[node + 1]);

    float den = 0.f, acc = 0.f, denB = 0.f, accB = 0.f;
    int i = beg;
    for (; i + 4 <= end; i += 4) {
        int4 s4 = *(const int4*)&srcs[i];          // uniform addr
        int s0 = __builtin_amdgcn_readfirstlane(s4.x);
        int s1 = __builtin_amdgcn_readfirstlane(s4.y);
        int s2 = __builtin_amdgcn_readfirstlane(s4.z);
        int s3 = __builtin_amdgcn_readfirstlane(s4.w);
        float2 e0 = alE[s0 * NH1 + head];          // saddr + head*8 (64B row)
        float2 e1 = alE[s1 * NH1 + head];
        float2 e2 = alE[s2 * NH1 + head];
        float2 e3 = alE[s3 * NH1 + head];
        unsigned short u0 = h1b[s0 * HC + lane];   // saddr + lane*2 (128B row)
        unsigned short u1 = h1b[s1 * HC + lane];
        unsigned short u2 = h1b[s2 * HC + lane];
        unsigned short u3 = h1b[s3 * HC + lane];
        float p0 = fmaxf(e0.x * E1d, e0.y * E2d);
        float p1 = fmaxf(e1.x * E1d, e1.y * E2d);
        float p2 = fmaxf(e2.x * E1d, e2.y * E2d);
        float p3 = fmaxf(e3.x * E1d, e3.y * E2d);
        den  += p0;  acc  = fmaf(p0, __uint_as_float((unsigned int)u0 << 16), acc);
        denB += p1;  accB = fmaf(p1, __uint_as_float((unsigned int)u1 << 16), accB);
        den  += p2;  acc  = fmaf(p2, __uint_as_float((unsigned int)u2 << 16), acc);
        denB += p3;  accB = fmaf(p3, __uint_as_float((unsigned int)u3 << 16), accB);
    }
    for (; i < end; ++i) {
        int s0 = __builtin_amdgcn_readfirstlane(srcs[i]);
        float2 e0 = alE[s0 * NH1 + head];
        unsigned short u0 = h1b[s0 * HC + lane];
        float p0 = fmaxf(e0.x * E1d, e0.y * E2d);
        den += p0; acc = fmaf(p0, __uint_as_float((unsigned int)u0 << 16), acc);
    }
    den += denB; acc += accB;

    float o = acc / den + b1[lane];
    o = (o > 0.f) ? o : expm1f(o);          // ELU
    // layer-2 linear: h2[node][oc] = sum_lane o * W2[lane][oc]
    float2 w2v = *(const float2*)&W2[lane * OUTC];
    float p0 = o * w2v.x;
    float p1 = o * w2v.y;
    for (int off = 1; off < 64; off <<= 1) {
        p0 += __shfl_xor(p0, off, 64);
        p1 += __shfl_xor(p1, off, 64);
    }
    if (lane == 0) {
        float l2s = p0 * a2s[0] + p1 * a2s[1];
        float l2d = p0 * a2d[0] + p1 * a2d[1];
        nd2[node] = make_float4(exp2f(l2s * L2E), exp2f(l2s * (NEGSL * L2E)),
                                p0, p1);
        al2d[node] = l2d;
    }
}

// ---------------- layer 2 aggregation (wave per node, lane per edge) ----------------

__global__ __launch_bounds__(256) void agg2(const float4* __restrict__ nd2,
                                            const float* __restrict__ al2d,
                                            const float* __restrict__ b2,
                                            const int* __restrict__ rowoff,
                                            const int* __restrict__ srcs,
                                            float* __restrict__ out) {
    int w = threadIdx.x >> 6, lane = threadIdx.x & 63;
    int n = blockIdx.x * 4 + w;
    if (n >= NNODES) return;
    float ald = al2d[n];
    float E1d = exp2f(ald * L2E);
    float E2d = exp2f(ald * (NEGSL * L2E));
    int beg = rowoff[n], end = rowoff[n + 1];
    float den = 0.f, a0 = 0.f, a1 = 0.f;
    for (int idx = beg + lane; idx < end; idx += 64) {
        int s = srcs[idx];
        float4 nd = nd2[s];
        float p = fmaxf(nd.x * E1d, nd.y * E2d);
        den += p;
        a0 = fmaf(p, nd.z, a0);
        a1 = fmaf(p, nd.w, a1);
    }
    for (int off = 1; off < 64; off <<= 1) {
        den += __shfl_xor(den, off, 64);
        a0  += __shfl_xor(a0, off, 64);
        a1  += __shfl_xor(a1, off, 64);
    }
    if (lane == 0) {
        out[n * 2 + 0] = a0 / den + b2[0];
        out[n * 2 + 1] = a1 / den + b2[1];
    }
}

// ---------------- launch ----------------

extern "C" void kernel_launch(void* const* d_in, const int* in_sizes, int n_in,
                              void* d_out, int out_size, void* d_ws, size_t ws_size,
                              hipStream_t stream) {
    const float* x   = (const float*)d_in[0];
    const int*   ei  = (const int*)  d_in[1];
    // d_in[2] = edge_attr (unused by reference)
    const float* W1  = (const float*)d_in[3];
    const float* a1s = (const float*)d_in[4];
    const float* a1d = (const float*)d_in[5];
    const float* b1  = (const float*)d_in[6];
    const float* W2  = (const float*)d_in[7];
    const float* a2s = (const float*)d_in[8];
    const float* a2d = (const float*)d_in[9];
    const float* b2  = (const float*)d_in[10];
    float* out = (float*)d_out;

    // workspace layout. CSR scratch (ebuf/carr/bsums) aliases the h1b+alE
    // region — both are dead until gemm1, which runs after buildD.
    char* ws = (char*)d_ws;
    unsigned short* h1b = (unsigned short*)ws;               // N*64 bf16 (12.8MB)
    float2* alE   = (float2*)(ws + (size_t)NNODES * HC * 2); // N*8 float2 (6.4MB)
    float* al1d_  = (float*)(alE + (size_t)NNODES * NH1);    // N*8 (3.2MB)
    float4* nd2   = (float4*)(al1d_ + (size_t)NNODES * NH1); // N float4 (1.6MB)
    float* al2d_  = (float*)(nd2 + NNODES);                  // N
    int* rowoff   = (int*)(al2d_ + NNODES);                  // N+1
    int* srcs     = rowoff + NNODES + 1;                     // E+N (13.2MB)
    // CSR scratch aliases h1b..alE (19.2MB >= 14.1MB needed)
    int* ebuf     = (int*)ws;                                // NEDGES (12.8MB)
    int* carr     = ebuf + NEDGES;                           // TOTC (1.22MB)
    int* bsums    = carr + TOTC;                             // ~1195 ints

    const int NB_SC  = (TOTC + 255) / 256;            // 1195
    const int NB_N4  = (NNODES + 3) / 4;              // 25000
    const int NB_G   = NNODES / 16;                   // 6250 (exact)

    // CSR build (LDS counting sort; no global atomics)
    histA<<<NBLK, 256, 0, stream>>>(ei, carr);
    scanA<<<NB_SC, 256, 0, stream>>>(carr, bsums);
    scanB<<<1, 1024, 0, stream>>>(bsums, NB_SC);
    scanC<<<NB_SC, 256, 0, stream>>>(carr, bsums);
    scatC<<<NBLK, 256, 0, stream>>>(ei, carr, ebuf);
    buildD<<<NBUCK, 256, 0, stream>>>(carr, ebuf, rowoff, srcs);

    // layer 1 linear + logit exponentials
    gemm1<<<NB_G, 256, 0, stream>>>(x, W1, a1s, a1d, h1b, alE, al1d_);

    // layer 1 aggregation + finalize + layer-2 linear/logits
    agg1<<<NB_N4, 256, 0, stream>>>(h1b, alE, al1d_, b1, W2, a2s, a2d,
                                    rowoff, srcs, nd2, al2d_);

    // layer 2 aggregation -> output
    agg2<<<NB_N4, 256, 0, stream>>>(nd2, al2d_, b2, rowoff, srcs, out);
}

// Round 18
// 268.887 us; speedup vs baseline: 1.7605x; 1.0267x over previous
//
#include <hip/hip_runtime.h>
#include <math.h>

#define NNODES 100000
#define NEDGES 3200000
#define ETOT   (NEDGES + NNODES)
#define IN_DIM 128
#define NH1    8
#define NC1    8
#define HC     64
#define OUTC   2
#define NEGSL  0.2f
#define L2E    1.44269504f

// counting-sort CSR build parameters
#define NBUCK 391                 // ceil(NNODES/256) coarse buckets (dst>>8)
#define EPB   4096                // edges per block in hist/scatter
#define NBLK  782                 // ceil(NEDGES/EPB)
#define TOTC  (NBUCK * NBLK)      // 305762 (bucket-major counts array)

// ---------------- CSR build (two-level LDS counting sort) ----------------

__global__ __launch_bounds__(256) void histA(const int* __restrict__ ei,
                                             int* __restrict__ carr) {
    __shared__ int lh[NBUCK];
    int tid = threadIdx.x;
    for (int i = tid; i < NBUCK; i += 256) lh[i] = 0;
    __syncthreads();
    const int* dptr = ei + NEDGES;
    int base = blockIdx.x * EPB;
#pragma unroll
    for (int i = 0; i < EPB / 1024; i++) {
        int idx = base + i * 1024 + tid * 4;
        if (idx < NEDGES) {
            int4 d4 = *(const int4*)&dptr[idx];
            atomicAdd(&lh[d4.x >> 8], 1);
            atomicAdd(&lh[d4.y >> 8], 1);
            atomicAdd(&lh[d4.z >> 8], 1);
            atomicAdd(&lh[d4.w >> 8], 1);
        }
    }
    __syncthreads();
    for (int i = tid; i < NBUCK; i += 256)
        carr[i * NBLK + blockIdx.x] = lh[i];
}

__global__ __launch_bounds__(256) void scanA(int* __restrict__ carr,
                                             int* __restrict__ bsums) {
    int gid = blockIdx.x * 256 + threadIdx.x;
    int v = (gid < TOTC) ? carr[gid] : 0;
    int lane = threadIdx.x & 63, w = threadIdx.x >> 6;
    int x = v;
    for (int off = 1; off < 64; off <<= 1) {
        int y = __shfl_up(x, off, 64);
        if (lane >= off) x += y;
    }
    __shared__ int wt[4];
    if (lane == 63) wt[w] = x;
    __syncthreads();
    int add = 0;
    for (int i = 0; i < w; i++) add += wt[i];
    int incl = x + add;
    if (gid < TOTC) carr[gid] = incl - v;
    if (threadIdx.x == 255) bsums[blockIdx.x] = incl;
}

__global__ __launch_bounds__(1024) void scanB(int* __restrict__ bsums, int nb) {
    int tid = threadIdx.x;
    int base = tid * 4;
    int v[4]; int tot = 0;
#pragma unroll
    for (int j = 0; j < 4; j++) {
        v[j] = (base + j < nb) ? bsums[base + j] : 0;
        tot += v[j];
    }
    int lane = tid & 63, w = tid >> 6;
    int x = tot;
    for (int off = 1; off < 64; off <<= 1) {
        int y = __shfl_up(x, off, 64);
        if (lane >= off) x += y;
    }
    __shared__ int wt[16];
    if (lane == 63) wt[w] = x;
    __syncthreads();
    int add = 0;
    for (int i = 0; i < w; i++) add += wt[i];
    int pre = x + add - tot;
#pragma unroll
    for (int j = 0; j < 4; j++) {
        if (base + j < nb) bsums[base + j] = pre;
        pre += v[j];
    }
}

__global__ __launch_bounds__(256) void scanC(int* __restrict__ carr,
                                             const int* __restrict__ bsums) {
    int gid = blockIdx.x * 256 + threadIdx.x;
    if (gid < TOTC) carr[gid] += bsums[gid >> 8];
}

__global__ __launch_bounds__(256) void scatC(const int* __restrict__ ei,
                                             const int* __restrict__ soff,
                                             int* __restrict__ ebuf) {
    __shared__ int soffL[NBUCK];
    __shared__ int lh[NBUCK];
    int tid = threadIdx.x;
    for (int i = tid; i < NBUCK; i += 256) {
        soffL[i] = soff[i * NBLK + blockIdx.x];
        lh[i] = 0;
    }
    __syncthreads();
    int base = blockIdx.x * EPB;
#pragma unroll
    for (int i = 0; i < EPB / 1024; i++) {
        int idx = base + i * 1024 + tid * 4;
        if (idx < NEDGES) {
            int4 s4 = *(const int4*)&ei[idx];
            int4 d4 = *(const int4*)&ei[NEDGES + idx];
            int b0 = d4.x >> 8, b1 = d4.y >> 8, b2 = d4.z >> 8, b3 = d4.w >> 8;
            int r0 = atomicAdd(&lh[b0], 1);
            int r1 = atomicAdd(&lh[b1], 1);
            int r2 = atomicAdd(&lh[b2], 1);
            int r3 = atomicAdd(&lh[b3], 1);
            ebuf[soffL[b0] + r0] = s4.x | ((d4.x & 255) << 17);
            ebuf[soffL[b1] + r1] = s4.y | ((d4.y & 255) << 17);
            ebuf[soffL[b2] + r2] = s4.z | ((d4.z & 255) << 17);
            ebuf[soffL[b3] + r3] = s4.w | ((d4.w & 255) << 17);
        }
    }
}

__global__ __launch_bounds__(256) void buildD(const int* __restrict__ soff,
                                              const int* __restrict__ ebuf,
                                              int* __restrict__ rowoff,
                                              int* __restrict__ srcs) {
    int b = blockIdx.x, tid = threadIdx.x;
    int nb = min(256, NNODES - b * 256);
    int ebeg = soff[b * NBLK];
    int eend = (b == NBUCK - 1) ? NEDGES : soff[(b + 1) * NBLK];
    __shared__ int cnt2[256];
    __shared__ int rowL[256];
    __shared__ int wsum[4];
    cnt2[tid] = 0;
    __syncthreads();
    for (int e = ebeg + tid; e < eend; e += 256)
        atomicAdd(&cnt2[(ebuf[e] >> 17) & 255], 1);
    __syncthreads();
    int v = (tid < nb) ? cnt2[tid] + 1 : 0;
    int lane = tid & 63, w = tid >> 6;
    int x = v;
    for (int off = 1; off < 64; off <<= 1) {
        int y = __shfl_up(x, off, 64);
        if (lane >= off) x += y;
    }
    if (lane == 63) wsum[w] = x;
    __syncthreads();
    int add = 0;
    for (int i = 0; i < w; i++) add += wsum[i];
    int fbase = ebeg + b * 256;
    int row = fbase + x + add - v;
    if (tid < nb) {
        rowL[tid] = row;
        int gnode = b * 256 + tid;
        rowoff[gnode] = row;
        srcs[row + cnt2[tid]] = gnode;
        if (gnode == NNODES - 1) rowoff[NNODES] = ETOT;
    }
    __syncthreads();
    cnt2[tid] = 0;
    __syncthreads();
    for (int e = ebeg + tid; e < eend; e += 256) {
        int wv = ebuf[e];
        int dl = (wv >> 17) & 255;
        int r = atomicAdd(&cnt2[dl], 1);
        srcs[rowL[dl] + r] = wv & 0x1FFFF;
    }
}

// ---------------- layer 1 linear + attention logit exponentials ----------------

__global__ __launch_bounds__(256) void gemm1(const float* __restrict__ x,
                                             const float* __restrict__ W1,
                                             const float* __restrict__ a1s,
                                             const float* __restrict__ a1d,
                                             unsigned short* __restrict__ h1b,
                                             float2* __restrict__ alE,
                                             float* __restrict__ al1d) {
    __shared__ float sW[IN_DIM * HC];   // 32 KB
    int tid = threadIdx.x;
    const float4* W4 = (const float4*)W1;
    float4* sW4 = (float4*)sW;
#pragma unroll
    for (int i = 0; i < 8; i++)
        sW4[tid + i * 256] = W4[tid + i * 256];
    __syncthreads();

    int w = __builtin_amdgcn_readfirstlane(tid >> 6);
    int lane = tid & 63;
    int node0 = blockIdx.x * 16 + w * 4;       // 6250 blocks * 16 = 100000 exact
    const float* xr = x + (size_t)node0 * IN_DIM;

    float acc0 = 0.f, acc1 = 0.f, acc2 = 0.f, acc3 = 0.f;
#pragma unroll 8
    for (int k = 0; k < IN_DIM; k++) {
        float wv = sW[k * HC + lane];
        acc0 = fmaf(xr[k], wv, acc0);
        acc1 = fmaf(xr[IN_DIM + k], wv, acc1);
        acc2 = fmaf(xr[2 * IN_DIM + k], wv, acc2);
        acc3 = fmaf(xr[3 * IN_DIM + k], wv, acc3);
    }

    float accs[4] = {acc0, acc1, acc2, acc3};
    int head = lane >> 3, c = lane & 7;
    float as = a1s[head * NC1 + c], adv = a1d[head * NC1 + c];
#pragma unroll
    for (int n = 0; n < 4; n++) {
        int node = node0 + n;
        unsigned int u = __float_as_uint(accs[n]);
        h1b[node * HC + lane] =
            (unsigned short)((u + 0x7FFF + ((u >> 16) & 1)) >> 16);  // RNE bf16
        float ps = accs[n] * as;
        float pd = accs[n] * adv;
        for (int off = 1; off < 8; off <<= 1) {
            ps += __shfl_xor(ps, off, 64);
            pd += __shfl_xor(pd, off, 64);
        }
        if (c == 0) {
            alE[node * NH1 + head] = make_float2(exp2f(ps * L2E),
                                                 exp2f(ps * (NEGSL * L2E)));
            al1d[node * NH1 + head] = pd;
        }
    }
}

// ---------------- layer 1 aggregation (R11 structure — best measured) ----------------
// wave per node; TWO edges per wave-instruction: lane = ep*32 + c where
// ep = edge parity, c = channel pair (channels 2c,2c+1; head = c>>2).
// exp(LeakyReLU(als+ald)) == max(E1s*E1d, E2s*E2d); shift cancels in acc/den.

__global__ __launch_bounds__(256) void agg1(const unsigned short* __restrict__ h1b,
                                            const float2* __restrict__ alE,
                                            const float* __restrict__ al1d,
                                            const float* __restrict__ b1,
                                            const float* __restrict__ W2,
                                            const float* __restrict__ a2s,
                                            const float* __restrict__ a2d,
                                            const int* __restrict__ rowoff,
                                            const int* __restrict__ srcs,
                                            float4* __restrict__ nd2,
                                            float* __restrict__ al2d) {
    int w = threadIdx.x >> 6, lane = threadIdx.x & 63;
    int node = blockIdx.x * 4 + w;
    if (node >= NNODES) return;
    int ep = lane >> 5;          // which edge of the pair
    int c  = lane & 31;          // channel pair id: channels 2c, 2c+1
    int hh = c >> 2;             // head of both channels
    float ald = al1d[node * NH1 + hh];
    float E1d = exp2f(ald * L2E);
    float E2d = exp2f(ald * (NEGSL * L2E));
    int beg = __builtin_amdgcn_readfirstlane(rowoff[node]);
    int end = __builtin_amdgcn_readfirstlane(rowoff[node + 1]);

    float den = 0.f, acc0 = 0.f, acc1 = 0.f;
    float denB = 0.f, acc0B = 0.f, acc1B = 0.f;
    int i = beg;
    for (; i + 4 <= end; i += 4) {
        int sa = srcs[i + ep];
        int sb = srcs[i + 2 + ep];
        float2 ea = alE[sa * NH1 + hh];
        float2 eb = alE[sb * NH1 + hh];
        unsigned int ha = *(const unsigned int*)&h1b[sa * HC + 2 * c];
        unsigned int hb = *(const unsigned int*)&h1b[sb * HC + 2 * c];
        float pa = fmaxf(ea.x * E1d, ea.y * E2d);
        float pb = fmaxf(eb.x * E1d, eb.y * E2d);
        float va0 = __uint_as_float(ha << 16);
        float va1 = __uint_as_float(ha & 0xFFFF0000u);
        float vb0 = __uint_as_float(hb << 16);
        float vb1 = __uint_as_float(hb & 0xFFFF0000u);
        den  += pa;  acc0  = fmaf(pa, va0, acc0);  acc1  = fmaf(pa, va1, acc1);
        denB += pb;  acc0B = fmaf(pb, vb0, acc0B); acc1B = fmaf(pb, vb1, acc1B);
    }
    for (; i < end; i += 2) {
        int ia = i + ep;
        bool valid = ia < end;
        int sa = srcs[valid ? ia : end - 1];
        float2 ea = alE[sa * NH1 + hh];
        unsigned int ha = *(const unsigned int*)&h1b[sa * HC + 2 * c];
        float pa = fmaxf(ea.x * E1d, ea.y * E2d);
        pa = valid ? pa : 0.f;
        float va0 = __uint_as_float(ha << 16);
        float va1 = __uint_as_float(ha & 0xFFFF0000u);
        den += pa; acc0 = fmaf(pa, va0, acc0); acc1 = fmaf(pa, va1, acc1);
    }
    den += denB; acc0 += acc0B; acc1 += acc1B;
    den  += __shfl_xor(den, 32, 64);
    acc0 += __shfl_xor(acc0, 32, 64);
    acc1 += __shfl_xor(acc1, 32, 64);

    float2 b1v = *(const float2*)&b1[2 * c];
    float o0 = acc0 / den + b1v.x;
    float o1 = acc1 / den + b1v.y;
    o0 = (o0 > 0.f) ? o0 : expm1f(o0);       // ELU
    o1 = (o1 > 0.f) ? o1 : expm1f(o1);
    float4 w2v = *(const float4*)&W2[4 * c];
    float p0 = o0 * w2v.x + o1 * w2v.z;
    float p1 = o0 * w2v.y + o1 * w2v.w;
    for (int off = 1; off < 32; off <<= 1) {
        p0 += __shfl_xor(p0, off, 64);
        p1 += __shfl_xor(p1, off, 64);
    }
    if (lane == 0) {
        float l2s = p0 * a2s[0] + p1 * a2s[1];
        float l2d = p0 * a2d[0] + p1 * a2d[1];
        nd2[node] = make_float4(exp2f(l2s * L2E), exp2f(l2s * (NEGSL * L2E)),
                                p0, p1);
        al2d[node] = l2d;
    }
}

// ---------------- layer 2 aggregation (wave per node, lane per edge) ----------------

__global__ __launch_bounds__(256) void agg2(const float4* __restrict__ nd2,
                                            const float* __restrict__ al2d,
                                            const float* __restrict__ b2,
                                            const int* __restrict__ rowoff,
                                            const int* __restrict__ srcs,
                                            float* __restrict__ out) {
    int w = threadIdx.x >> 6, lane = threadIdx.x & 63;
    int n = blockIdx.x * 4 + w;
    if (n >= NNODES) return;
    float ald = al2d[n];
    float E1d = exp2f(ald * L2E);
    float E2d = exp2f(ald * (NEGSL * L2E));
    int beg = rowoff[n], end = rowoff[n + 1];
    float den = 0.f, a0 = 0.f, a1 = 0.f;
    for (int idx = beg + lane; idx < end; idx += 64) {
        int s = srcs[idx];
        float4 nd = nd2[s];
        float p = fmaxf(nd.x * E1d, nd.y * E2d);
        den += p;
        a0 = fmaf(p, nd.z, a0);
        a1 = fmaf(p, nd.w, a1);
    }
    for (int off = 1; off < 64; off <<= 1) {
        den += __shfl_xor(den, off, 64);
        a0  += __shfl_xor(a0, off, 64);
        a1  += __shfl_xor(a1, off, 64);
    }
    if (lane == 0) {
        out[n * 2 + 0] = a0 / den + b2[0];
        out[n * 2 + 1] = a1 / den + b2[1];
    }
}

// ---------------- launch ----------------

extern "C" void kernel_launch(void* const* d_in, const int* in_sizes, int n_in,
                              void* d_out, int out_size, void* d_ws, size_t ws_size,
                              hipStream_t stream) {
    const float* x   = (const float*)d_in[0];
    const int*   ei  = (const int*)  d_in[1];
    // d_in[2] = edge_attr (unused by reference)
    const float* W1  = (const float*)d_in[3];
    const float* a1s = (const float*)d_in[4];
    const float* a1d = (const float*)d_in[5];
    const float* b1  = (const float*)d_in[6];
    const float* W2  = (const float*)d_in[7];
    const float* a2s = (const float*)d_in[8];
    const float* a2d = (const float*)d_in[9];
    const float* b2  = (const float*)d_in[10];
    float* out = (float*)d_out;

    // workspace layout. CSR scratch (ebuf/carr/bsums) aliases the h1b+alE
    // region — both are dead until gemm1, which runs after buildD.
    char* ws = (char*)d_ws;
    unsigned short* h1b = (unsigned short*)ws;               // N*64 bf16 (12.8MB)
    float2* alE   = (float2*)(ws + (size_t)NNODES * HC * 2); // N*8 float2 (6.4MB)
    float* al1d_  = (float*)(alE + (size_t)NNODES * NH1);    // N*8 (3.2MB)
    float4* nd2   = (float4*)(al1d_ + (size_t)NNODES * NH1); // N float4 (1.6MB)
    float* al2d_  = (float*)(nd2 + NNODES);                  // N
    int* rowoff   = (int*)(al2d_ + NNODES);                  // N+1
    int* srcs     = rowoff + NNODES + 1;                     // E+N (13.2MB)
    // CSR scratch aliases h1b..alE (19.2MB >= 14.1MB needed)
    int* ebuf     = (int*)ws;                                // NEDGES (12.8MB)
    int* carr     = ebuf + NEDGES;                           // TOTC (1.22MB)
    int* bsums    = carr + TOTC;                             // ~1195 ints

    const int NB_SC  = (TOTC + 255) / 256;            // 1195
    const int NB_N4  = (NNODES + 3) / 4;              // 25000
    const int NB_G   = NNODES / 16;                   // 6250 (exact)

    // CSR build (LDS counting sort; no global atomics)
    histA<<<NBLK, 256, 0, stream>>>(ei, carr);
    scanA<<<NB_SC, 256, 0, stream>>>(carr, bsums);
    scanB<<<1, 1024, 0, stream>>>(bsums, NB_SC);
    scanC<<<NB_SC, 256, 0, stream>>>(carr, bsums);
    scatC<<<NBLK, 256, 0, stream>>>(ei, carr, ebuf);
    buildD<<<NBUCK, 256, 0, stream>>>(carr, ebuf, rowoff, srcs);

    // layer 1 linear + logit exponentials
    gemm1<<<NB_G, 256, 0, stream>>>(x, W1, a1s, a1d, h1b, alE, al1d_);

    // layer 1 aggregation + finalize + layer-2 linear/logits
    agg1<<<NB_N4, 256, 0, stream>>>(h1b, alE, al1d_, b1, W2, a2s, a2d,
                                    rowoff, srcs, nd2, al2d_);

    // layer 2 aggregation -> output
    agg2<<<NB_N4, 256, 0, stream>>>(nd2, al2d_, b2, rowoff, srcs, out);
}